// Round 8
// baseline (289.941 us; speedup 1.0000x reference)
//
#include <hip/hip_runtime.h>
#include <hip/hip_bf16.h>

// BatchSplitFF: DM=1024, NEXPERTS=32, SETS=4 (ES=128 pairs), ESIZE=32, B=2, S=8192
#define DM   1024
#define NES  128
#define GT   32
#define NGRP 512
#define FSZ  32

typedef float f32x4 __attribute__((ext_vector_type(4)));
typedef short s16x8 __attribute__((ext_vector_type(8)));

// async global->LDS, 16B per lane; LDS dest must be wave-uniform base.
#define GL2LDS(gp, lp) __builtin_amdgcn_global_load_lds(                      \
    (const __attribute__((address_space(1))) void*)(gp),                     \
    (__attribute__((address_space(3))) void*)(lp), 16, 0, 0)

__device__ inline unsigned short f2bf(float f) {   // RNE f32->bf16
  union { float f; unsigned int u; } x; x.f = f;
  unsigned int r = x.u + 0x7fffu + ((x.u >> 16) & 1u);
  return (unsigned short)(r >> 16);
}
__device__ inline float bf2f(unsigned short h) {
  union { unsigned int u; float f; } x; x.u = ((unsigned int)h) << 16;
  return x.f;
}

// ---------------------------------------------------------------------------
// Kernel A: controller logits (f32) + argmax mask + x->bf16 emission.
// v5: Wc reads moved OFF the per-CU LDS pipe to global float4 (L1/L2-hot,
// offset-folded). Only x lives in LDS (128-dd chunks, async dbuf, broadcast
// reads). 16 outputs/thread (4es x 4t). Per-output fmaf chain + part[] flush
// cadence BIT-IDENTICAL to r1-r7 (argmax unchanged).
// ---------------------------------------------------------------------------
__global__ __launch_bounds__(256, 2) void kA(const float* __restrict__ x,
                                             const float* __restrict__ Wc,
                                             const float* __restrict__ bc,
                                             unsigned int* __restrict__ sel,
                                             unsigned short* __restrict__ xb) {
  __shared__ float smem[8192];                   // 32 KB
  float* const xsA = smem;                       // [32t][128dd] 16 KB
  float* const xsB = smem + 4096;
  float* const lg  = smem;                       // alias xsA (epilogue only)
  const int g   = blockIdx.x;
  const int tid = threadIdx.x;
  const int l   = tid & 63, w = tid >> 6;        // 4 waves
  const int es0 = (tid & 31) * 4;
  const int t0  = (tid >> 5) * 4;
  const float* xg = x + (size_t)g * GT * DM;
  const float* wbase = Wc + es0;

  float acc[16], part[16];
#pragma unroll
  for (int i = 0; i < 16; ++i) acc[i] = 0.f;

  // stage 128-dd x chunk (16 KB): 16 GL2LDS insts (4/wave), 2 rows each.
  auto STAGE = [&](int c, float* dst) {
    const int d0 = c * 128;
#pragma unroll
    for (int kk = 0; kk < 4; ++kk) {
      const int inst = w * 4 + kk;               // [0,16): rows inst*2..+1
      GL2LDS(xg + (size_t)(inst * 2 + (l >> 5)) * DM + d0 + (l & 31) * 4,
             dst + inst * 256);                  // wave-uniform LDS base
    }
  };

  STAGE(0, xsA);
  asm volatile("s_waitcnt vmcnt(0)" ::: "memory");
  __syncthreads();

  for (int c = 0; c < 8; ++c) {
    const int d0 = c * 128;
    const float* xp = (c & 1) ? xsB : xsA;
    if (c < 7) STAGE(c + 1, (c & 1) ? xsA : xsB);

    // emit bf16 x chunk (contiguous LDS reads, coalesced stores)
#pragma unroll
    for (int j = 0; j < 4; ++j) {
      int idx = j * 1024 + tid * 4;              // f32 idx in [0,4096)
      int t = idx >> 7, col = idx & 127;
      float4 a4 = *(const float4*)&xp[idx];
      short4 v;
      v.x = (short)f2bf(a4.x); v.y = (short)f2bf(a4.y);
      v.z = (short)f2bf(a4.z); v.w = (short)f2bf(a4.w);
      *(short4*)&xb[((size_t)g * GT + t) * DM + d0 + col] = v;
    }

#pragma unroll
    for (int h = 0; h < 2; ++h) {                // 64-dd halves (flush cadence)
#pragma unroll
      for (int i = 0; i < 16; ++i) part[i] = 0.f;
#pragma unroll 4
      for (int s = 0; s < 16; ++s) {
        const int dd = h * 64 + s * 4;           // local dd in chunk
        const size_t wrow = (size_t)(d0 + dd) * NES;
        float4 w0 = *(const float4*)&wbase[wrow];          // global, L1/L2-hot
        float4 w1 = *(const float4*)&wbase[wrow + 128];
        float4 w2 = *(const float4*)&wbase[wrow + 256];
        float4 w3 = *(const float4*)&wbase[wrow + 384];
        float4 xv0 = *(const float4*)&xp[(t0 + 0) * 128 + dd];  // LDS broadcast
        float4 xv1 = *(const float4*)&xp[(t0 + 1) * 128 + dd];
        float4 xv2 = *(const float4*)&xp[(t0 + 2) * 128 + dd];
        float4 xv3 = *(const float4*)&xp[(t0 + 3) * 128 + dd];
#define KSTEP(i, XV)                                                       \
        part[i*4+0] = fmaf(XV.x, w0.x, part[i*4+0]);                       \
        part[i*4+1] = fmaf(XV.x, w0.y, part[i*4+1]);                       \
        part[i*4+2] = fmaf(XV.x, w0.z, part[i*4+2]);                       \
        part[i*4+3] = fmaf(XV.x, w0.w, part[i*4+3]);                       \
        part[i*4+0] = fmaf(XV.y, w1.x, part[i*4+0]);                       \
        part[i*4+1] = fmaf(XV.y, w1.y, part[i*4+1]);                       \
        part[i*4+2] = fmaf(XV.y, w1.z, part[i*4+2]);                       \
        part[i*4+3] = fmaf(XV.y, w1.w, part[i*4+3]);                       \
        part[i*4+0] = fmaf(XV.z, w2.x, part[i*4+0]);                       \
        part[i*4+1] = fmaf(XV.z, w2.y, part[i*4+1]);                       \
        part[i*4+2] = fmaf(XV.z, w2.z, part[i*4+2]);                       \
        part[i*4+3] = fmaf(XV.z, w2.w, part[i*4+3]);                       \
        part[i*4+0] = fmaf(XV.w, w3.x, part[i*4+0]);                       \
        part[i*4+1] = fmaf(XV.w, w3.y, part[i*4+1]);                       \
        part[i*4+2] = fmaf(XV.w, w3.z, part[i*4+2]);                       \
        part[i*4+3] = fmaf(XV.w, w3.w, part[i*4+3]);
        KSTEP(0, xv0) KSTEP(1, xv1) KSTEP(2, xv2) KSTEP(3, xv3)
#undef KSTEP
      }
#pragma unroll
      for (int i = 0; i < 16; ++i) acc[i] += part[i];
    }
    asm volatile("s_waitcnt vmcnt(0)" ::: "memory");
    __syncthreads();                             // chunk c+1 resident
  }

  // epilogue (unchanged numerics); lg aliases xsA — all compute is done.
#pragma unroll
  for (int i = 0; i < 4; ++i) {
    int t = t0 + i;
    float tie = (float)((double)t * (1e-6 / 31.0));
#pragma unroll
    for (int j = 0; j < 4; ++j) {
      int es = es0 + j;
      lg[t * NES + es] = (acc[i * 4 + j] + bc[es]) + tie;
    }
  }
  __syncthreads();
  if (tid < NES) {
    float m = -INFINITY;
    for (int t = 0; t < GT; ++t) m = fmaxf(m, lg[t * NES + tid]);
    unsigned int msk = 0u;
    for (int t = 0; t < GT; ++t) if (lg[t * NES + tid] == m) msk |= (1u << t);
    sel[(size_t)g * NES + tid] = msk;
  }
}

// ---------------------------------------------------------------------------
// kW: merged weight repack (one launch). Blocks [0,2048): W1 -> bf16 B-frag
// (K=d, N=f). Blocks [2048,4096): W2 -> bf16 B-frag (K=f, N=d).
// ---------------------------------------------------------------------------
__global__ __launch_bounds__(256) void kW(const float* __restrict__ W1,
                                          const float* __restrict__ W2,
                                          unsigned short* __restrict__ W1f,
                                          unsigned short* __restrict__ W2f) {
  const int bid = blockIdx.x;
  if (bid < 2048) {
    int idx = bid * 256 + threadIdx.x;             // (es, kt, nh, lane)
    int l = idx & 63, nh = (idx >> 6) & 1, kt = (idx >> 7) & 31, es = idx >> 12;
    const float* src = W1 + ((size_t)es * DM + kt * 32 + (l >> 4) * 8) * FSZ
                          + nh * 16 + (l & 15);
    s16x8 v;
#pragma unroll
    for (int i = 0; i < 8; ++i) v[i] = (short)f2bf(src[(size_t)i * FSZ]);
    *(s16x8*)(W1f + (size_t)idx * 8) = v;
  } else {
    int idx = (bid - 2048) * 256 + threadIdx.x;    // (es, dt, lane)
    int l = idx & 63, dt = (idx >> 6) & 63, es = idx >> 12;
    const float* src = W2 + ((size_t)es * DM + dt * 16 + (l & 15)) * FSZ + (l >> 4) * 8;
    float4 a = *(const float4*)src;
    float4 b = *(const float4*)(src + 4);
    s16x8 v;
    v[0] = (short)f2bf(a.x); v[1] = (short)f2bf(a.y);
    v[2] = (short)f2bf(a.z); v[3] = (short)f2bf(a.w);
    v[4] = (short)f2bf(b.x); v[5] = (short)f2bf(b.y);
    v[6] = (short)f2bf(b.z); v[7] = (short)f2bf(b.w);
    *(s16x8*)(W2f + (size_t)idx * 8) = v;
  }
}

// ---------------------------------------------------------------------------
// kBm: inner = relu(xsel . W1[es] + b1[es]) via MFMA (unchanged from r4/r5).
// ---------------------------------------------------------------------------
__global__ __launch_bounds__(256, 2) void kBm(const unsigned short* __restrict__ xb,
                                              const unsigned short* __restrict__ W1f,
                                              const float* __restrict__ b1,
                                              const unsigned int* __restrict__ sel,
                                              unsigned short* __restrict__ innerb) {
  __shared__ unsigned short As[128 * 128];   // [row][k] bf16, byte^((row&7)<<4)
  __shared__ int tokL[128];
  __shared__ unsigned int mulL[128];
  const int bid = blockIdx.x;
  const int es = bid >> 2, g0 = (bid & 3) * 128;
  const int tid = threadIdx.x;
  const int l = tid & 63, w = tid >> 6;
  const int r15 = l & 15, q = l >> 4;
  const int mw = w * 32;

  if (tid < 128) {
    unsigned int m = sel[(size_t)(g0 + tid) * NES + es];
    tokL[tid] = (g0 + tid) * GT + (__ffs(m) - 1);
    mulL[tid] = (m & (m - 1)) ? m : 0u;
  }

  const int r = tid >> 1, p = tid & 1;
  const int swz = (r & 7) << 4;
  const unsigned int dbase = (unsigned int)r * 256 + (unsigned int)p * 128;

  f32x4 acc[2][2];
#pragma unroll
  for (int i = 0; i < 2; ++i)
#pragma unroll
    for (int j = 0; j < 2; ++j) acc[i][j] = (f32x4){0.f, 0.f, 0.f, 0.f};

  for (int c = 0; c < 8; ++c) {
    __syncthreads();
    unsigned int mm = mulL[r];
    if (!mm) {
      const unsigned short* src = xb + (size_t)tokL[r] * DM + c * 128 + p * 64;
#pragma unroll
      for (int j = 0; j < 8; ++j) {
        s16x8 v = *(const s16x8*)(src + j * 8);
        *(s16x8*)((char*)As + ((dbase + j * 16) ^ swz)) = v;
      }
    } else {
      size_t grow = (size_t)(g0 + r) * GT;
#pragma unroll
      for (int j = 0; j < 8; ++j) {
        float av[8] = {0.f, 0.f, 0.f, 0.f, 0.f, 0.f, 0.f, 0.f};
        unsigned int m2 = mm;
        while (m2) {
          int tt = __ffs(m2) - 1; m2 &= m2 - 1;
          s16x8 v = *(const s16x8*)(xb + (grow + tt) * DM + c * 128 + p * 64 + j * 8);
#pragma unroll
          for (int k = 0; k < 8; ++k) av[k] += bf2f((unsigned short)v[k]);
        }
        s16x8 o;
#pragma unroll
        for (int k = 0; k < 8; ++k) o[k] = (short)f2bf(av[k]);
        *(s16x8*)((char*)As + ((dbase + j * 16) ^ swz)) = o;
      }
    }
    __syncthreads();

#pragma unroll
    for (int s = 0; s < 4; ++s) {
      const int ks = c * 4 + s;
      const unsigned short* bp = W1f + ((size_t)es * 32 + ks) * 1024 + l * 8;
      s16x8 bf0 = *(const s16x8*)bp;
      s16x8 bf1 = *(const s16x8*)(bp + 512);
      const int row0 = mw + r15, row1 = mw + 16 + r15;
      s16x8 a0 = *(const s16x8*)((char*)As +
                   (((unsigned)row0 * 256 + s * 64 + q * 16) ^ ((row0 & 7) << 4)));
      s16x8 a1 = *(const s16x8*)((char*)As +
                   (((unsigned)row1 * 256 + s * 64 + q * 16) ^ ((row1 & 7) << 4)));
      acc[0][0] = __builtin_amdgcn_mfma_f32_16x16x32_bf16(a0, bf0, acc[0][0], 0, 0, 0);
      acc[0][1] = __builtin_amdgcn_mfma_f32_16x16x32_bf16(a0, bf1, acc[0][1], 0, 0, 0);
      acc[1][0] = __builtin_amdgcn_mfma_f32_16x16x32_bf16(a1, bf0, acc[1][0], 0, 0, 0);
      acc[1][1] = __builtin_amdgcn_mfma_f32_16x16x32_bf16(a1, bf1, acc[1][1], 0, 0, 0);
    }
  }

  float bia0 = b1[es * FSZ + r15];
  float bia1 = b1[es * FSZ + 16 + r15];
#pragma unroll
  for (int i = 0; i < 2; ++i)
#pragma unroll
    for (int rr = 0; rr < 4; ++rr) {
      int g = g0 + mw + i * 16 + q * 4 + rr;
      unsigned short* op = innerb + ((size_t)es * NGRP + g) * FSZ;
      op[r15]      = f2bf(fmaxf(acc[i][0][rr] + bia0, 0.f));
      op[16 + r15] = f2bf(fmaxf(acc[i][1][rr] + bia1, 0.f));
    }
}

// ---------------------------------------------------------------------------
// kC1: per-es dense GEMM (512g x 32f).(32f x 1024d) -> Rb bf16 [g][Ec][d],
// b2 folded (unchanged).
// ---------------------------------------------------------------------------
__global__ __launch_bounds__(256) void kC1(const unsigned short* __restrict__ innerb,
                                           const unsigned short* __restrict__ W2f,
                                           const float* __restrict__ b2,
                                           unsigned short* __restrict__ Rb,
                                           int es0, int Ec) {
  const int bid = blockIdx.x;
  const int esl = bid >> 5;
  const int es  = es0 + esl;
  const int mt  = (bid >> 3) & 3;
  const int nt  = bid & 7;
  const int tid = threadIdx.x;
  const int l = tid & 63, w = tid >> 6;
  const int r15 = l & 15, q = l >> 4;
  const int g0 = mt * 128 + (w >> 1) * 64;
  const int n0 = nt * 128 + (w & 1) * 64;

  const unsigned short* Ab = innerb + ((size_t)es * NGRP + g0 + r15) * FSZ + q * 8;
  const unsigned short* Bb = W2f + (((size_t)es * 64 + (n0 >> 4)) * 64 + l) * 8;
  s16x8 a[4], b[4];
#pragma unroll
  for (int i = 0; i < 4; ++i) a[i] = *(const s16x8*)(Ab + (size_t)i * 16 * FSZ);
#pragma unroll
  for (int j = 0; j < 4; ++j) b[j] = *(const s16x8*)(Bb + (size_t)j * 64 * 8);

  const f32x4 z = {0.f, 0.f, 0.f, 0.f};
  f32x4 acc[4][4];
#pragma unroll
  for (int i = 0; i < 4; ++i)
#pragma unroll
    for (int j = 0; j < 4; ++j)
      acc[i][j] = __builtin_amdgcn_mfma_f32_16x16x32_bf16(a[i], b[j], z, 0, 0, 0);

#pragma unroll
  for (int j = 0; j < 4; ++j) {
    const int col = n0 + j * 16 + r15;
    const float b2v = b2[(size_t)es * DM + col];
#pragma unroll
    for (int i = 0; i < 4; ++i) {
#pragma unroll
      for (int r = 0; r < 4; ++r) {
        const int g = g0 + i * 16 + q * 4 + r;
        Rb[((size_t)g * Ec + esl) * DM + col] = f2bf(acc[i][j][r] + b2v);
      }
    }
  }
}

// ---------------------------------------------------------------------------
// kC2: per-(group, d-quarter) gather-combine (unchanged from r5).
// ---------------------------------------------------------------------------
__global__ __launch_bounds__(256) void kC2(const unsigned short* __restrict__ Rb,
                                           const unsigned int* __restrict__ sel,
                                           float* __restrict__ out,
                                           int es0, int Ec, int direct) {
  __shared__ unsigned int cnt[32];
  __shared__ unsigned char list[32][128];
  const int bid = blockIdx.x;
  const int g = bid >> 2, dq = bid & 3;
  const int tid = threadIdx.x;
  if (tid < 32) cnt[tid] = 0;
  __syncthreads();
  if (tid < Ec) {
    unsigned int m = sel[(size_t)g * NES + es0 + tid];
    while (m) { int t = __ffs(m) - 1; m &= m - 1;
      unsigned int p = atomicAdd(&cnt[t], 1u);
      list[t][p] = (unsigned char)tid; }
  }
  __syncthreads();
  const int t = tid >> 3, part = tid & 7;
  const int d0 = dq * 256 + part * 32;
  const int n = (int)cnt[t];
  const unsigned short* base = Rb + (size_t)g * Ec * DM + d0;

  float acc[32];
#pragma unroll
  for (int i = 0; i < 32; ++i) acc[i] = 0.f;

  s16x8 cur[4];
  if (n) {
    const unsigned short* r = base + (size_t)list[t][0] * DM;
#pragma unroll
    for (int v = 0; v < 4; ++v) cur[v] = *(const s16x8*)(r + v * 8);
  }
  for (int e = 0; e < n; ++e) {
    s16x8 nxt[4];
    const bool more = (e + 1 < n);
    if (more) {
      const unsigned short* r = base + (size_t)list[t][e + 1] * DM;
#pragma unroll
      for (int v = 0; v < 4; ++v) nxt[v] = *(const s16x8*)(r + v * 8);
    }
#pragma unroll
    for (int v = 0; v < 4; ++v)
#pragma unroll
      for (int k = 0; k < 8; ++k)
        acc[v * 8 + k] += bf2f((unsigned short)cur[v][k]);
    if (more) {
#pragma unroll
      for (int v = 0; v < 4; ++v) cur[v] = nxt[v];
    }
  }

  float* op = out + ((size_t)g * GT + t) * DM + d0;
  if (direct) {
#pragma unroll
    for (int v = 0; v < 8; ++v)
      *(float4*)&op[v * 4] =
          make_float4(acc[v * 4], acc[v * 4 + 1], acc[v * 4 + 2], acc[v * 4 + 3]);
  } else {
#pragma unroll
    for (int v = 0; v < 8; ++v) {
      float4 o = *(float4*)&op[v * 4];
      o.x += acc[v * 4]; o.y += acc[v * 4 + 1];
      o.z += acc[v * 4 + 2]; o.w += acc[v * 4 + 3];
      *(float4*)&op[v * 4] = o;
    }
  }
}

extern "C" void kernel_launch(void* const* d_in, const int* in_sizes, int n_in,
                              void* d_out, int out_size, void* d_ws, size_t ws_size,
                              hipStream_t stream) {
  const float* x  = (const float*)d_in[0];
  const float* Wc = (const float*)d_in[1];
  const float* bc = (const float*)d_in[2];
  const float* W1 = (const float*)d_in[3];
  const float* b1 = (const float*)d_in[4];
  const float* W2 = (const float*)d_in[5];
  const float* b2 = (const float*)d_in[6];
  float* out = (float*)d_out;

  // ws: sel @0 (256 KB); innerb @1M (4 MB); W2f @6M (8.4 MB);
  //     W1f @15M (8.4 MB, dead after kBm); xb @24M (33.5 MB, dead after kBm);
  //     Rb @15M overlapping W1f+xb (sequential stream => safe).
  unsigned int* sel = (unsigned int*)d_ws;
  unsigned short* innerb = (unsigned short*)((char*)d_ws + (1u << 20));
  unsigned short* W2f = (unsigned short*)((char*)d_ws + (6u << 20));
  unsigned short* W1f = (unsigned short*)((char*)d_ws + (15u << 20));
  unsigned short* xb  = (unsigned short*)((char*)d_ws + (24u << 20));
  unsigned short* Rb  = (unsigned short*)((char*)d_ws + (15u << 20));

  int Ec = 128;
  while (Ec > 1 && (15u << 20) + (size_t)NGRP * Ec * DM * 2 > ws_size) Ec >>= 1;
  const int NC = NES / Ec;

  if (NC > 1)
    hipMemsetAsync(d_out, 0, (size_t)out_size * sizeof(float), stream);
  kA<<<NGRP, 256, 0, stream>>>(x, Wc, bc, sel, xb);
  kW<<<4096, 256, 0, stream>>>(W1, W2, W1f, W2f);
  kBm<<<NGRP, 256, 0, stream>>>(xb, W1f, b1, sel, innerb);
  for (int c = 0; c < NC; ++c) {
    kC1<<<Ec * 32, 256, 0, stream>>>(innerb, W2f, b2, Rb, c * Ec, Ec);
    kC2<<<NGRP * 4, 256, 0, stream>>>(Rb, sel, out, c * Ec, Ec, NC == 1);
  }
}

// Round 9
// 239.216 us; speedup vs baseline: 1.2120x; 1.2120x over previous
//
#include <hip/hip_runtime.h>
#include <hip/hip_bf16.h>

// BatchSplitFF: DM=1024, NEXPERTS=32, SETS=4 (ES=128 pairs), ESIZE=32, B=2, S=8192
#define DM   1024
#define NES  128
#define GT   32
#define NGRP 512
#define FSZ  32
#define MARGIN_EPS 1e-3f   // > 4x deterministic bound on 3-term bf16-split error

typedef float f32x4 __attribute__((ext_vector_type(4)));
typedef short s16x8 __attribute__((ext_vector_type(8)));

__device__ inline unsigned short f2bf(float f) {   // RNE f32->bf16
  union { float f; unsigned int u; } x; x.f = f;
  unsigned int r = x.u + 0x7fffu + ((x.u >> 16) & 1u);
  return (unsigned short)(r >> 16);
}
__device__ inline float bf2f(unsigned short h) {
  union { unsigned int u; float f; } x; x.u = ((unsigned int)h) << 16;
  return x.f;
}

// ---------------------------------------------------------------------------
// kSplit: x f32 -> xh (bf16, == xb consumed by kBm/kLg) + xl (bf16 residual,
// consumed by kLg only).
// ---------------------------------------------------------------------------
__global__ __launch_bounds__(256) void kSplit(const float* __restrict__ x,
                                              unsigned short* __restrict__ xh,
                                              unsigned short* __restrict__ xl) {
  size_t i = ((size_t)blockIdx.x * 256 + threadIdx.x) * 8;
  float4 a = *(const float4*)&x[i];
  float4 b = *(const float4*)&x[i + 4];
  float v[8] = {a.x, a.y, a.z, a.w, b.x, b.y, b.z, b.w};
  s16x8 h, lo;
#pragma unroll
  for (int k = 0; k < 8; ++k) {
    unsigned short hh = f2bf(v[k]);
    h[k]  = (short)hh;
    lo[k] = (short)f2bf(v[k] - bf2f(hh));
  }
  *(s16x8*)&xh[i] = h;
  *(s16x8*)&xl[i] = lo;
}

// ---------------------------------------------------------------------------
// kW: merged weight repack. [0,2048): W1 -> bf16 B-frag (K=d, N=f).
// [2048,4096): W2 -> bf16 B-frag (K=f, N=d). [4096,4160): Wc -> hi/lo bf16
// B-frag (K=d, N=es): Wcf[((kt*8+nt)*64+l)*8+i] = Wc[kt*32+(l>>4)*8+i][nt*16+(l&15)].
// ---------------------------------------------------------------------------
__global__ __launch_bounds__(256) void kW(const float* __restrict__ W1,
                                          const float* __restrict__ W2,
                                          const float* __restrict__ Wc,
                                          unsigned short* __restrict__ W1f,
                                          unsigned short* __restrict__ W2f,
                                          unsigned short* __restrict__ Wchf,
                                          unsigned short* __restrict__ Wclf) {
  const int bid = blockIdx.x;
  if (bid < 2048) {
    int idx = bid * 256 + threadIdx.x;             // (es, kt, nh, lane)
    int l = idx & 63, nh = (idx >> 6) & 1, kt = (idx >> 7) & 31, es = idx >> 12;
    const float* src = W1 + ((size_t)es * DM + kt * 32 + (l >> 4) * 8) * FSZ
                          + nh * 16 + (l & 15);
    s16x8 v;
#pragma unroll
    for (int i = 0; i < 8; ++i) v[i] = (short)f2bf(src[(size_t)i * FSZ]);
    *(s16x8*)(W1f + (size_t)idx * 8) = v;
  } else if (bid < 4096) {
    int idx = (bid - 2048) * 256 + threadIdx.x;    // (es, dt, lane)
    int l = idx & 63, dt = (idx >> 6) & 63, es = idx >> 12;
    const float* src = W2 + ((size_t)es * DM + dt * 16 + (l & 15)) * FSZ + (l >> 4) * 8;
    float4 a = *(const float4*)src;
    float4 b = *(const float4*)(src + 4);
    s16x8 v;
    v[0] = (short)f2bf(a.x); v[1] = (short)f2bf(a.y);
    v[2] = (short)f2bf(a.z); v[3] = (short)f2bf(a.w);
    v[4] = (short)f2bf(b.x); v[5] = (short)f2bf(b.y);
    v[6] = (short)f2bf(b.z); v[7] = (short)f2bf(b.w);
    *(s16x8*)(W2f + (size_t)idx * 8) = v;
  } else {
    int idx = (bid - 4096) * 256 + threadIdx.x;    // (kt, nt, lane) in [0,16384)
    int l = idx & 63, nt = (idx >> 6) & 7, kt = idx >> 9;
    const float* src = Wc + (size_t)(kt * 32 + (l >> 4) * 8) * NES + nt * 16 + (l & 15);
    s16x8 h, lo;
#pragma unroll
    for (int i = 0; i < 8; ++i) {
      float v = src[(size_t)i * NES];
      unsigned short hh = f2bf(v);
      h[i]  = (short)hh;
      lo[i] = (short)f2bf(v - bf2f(hh));
    }
    *(s16x8*)(Wchf + (size_t)idx * 8) = h;
    *(s16x8*)(Wclf + (size_t)idx * 8) = lo;
  }
}

// ---------------------------------------------------------------------------
// kLg: controller logits via MFMA (3-term bf16 split: xh.wh + xl.wh + xh.wl).
// Per group: (32t x 128es), K=1024 per term. Certified-margin selection:
// margin > EPS -> bf16 argmax == f32 argmax, emit sel; else append to flag
// list for exact f32 recompute in kFix.
// ---------------------------------------------------------------------------
__global__ __launch_bounds__(256, 2) void kLg(const unsigned short* __restrict__ xh,
                                              const unsigned short* __restrict__ xl,
                                              const unsigned short* __restrict__ Wchf,
                                              const unsigned short* __restrict__ Wclf,
                                              const float* __restrict__ bc,
                                              unsigned int* __restrict__ sel,
                                              unsigned int* __restrict__ flags,
                                              unsigned int* __restrict__ cnt) {
  __shared__ float lg[GT * NES];                   // 16 KB
  const int g   = blockIdx.x;
  const int tid = threadIdx.x;
  const int l   = tid & 63, w = tid >> 6;          // wave w owns es [w*32, w*32+32)
  const int r15 = l & 15, q = l >> 4;

  const unsigned short* ah0 = xh + ((size_t)g * GT + r15) * DM + q * 8;
  const unsigned short* ah1 = ah0 + 16 * DM;
  const unsigned short* al0 = xl + ((size_t)g * GT + r15) * DM + q * 8;
  const unsigned short* al1 = al0 + 16 * DM;

  f32x4 acc[2][2];
#pragma unroll
  for (int i = 0; i < 2; ++i)
#pragma unroll
    for (int j = 0; j < 2; ++j) acc[i][j] = (f32x4){0.f, 0.f, 0.f, 0.f};

  for (int kt = 0; kt < 32; ++kt) {
    s16x8 Ah0 = *(const s16x8*)(ah0 + kt * 32);
    s16x8 Ah1 = *(const s16x8*)(ah1 + kt * 32);
    s16x8 Al0 = *(const s16x8*)(al0 + kt * 32);
    s16x8 Al1 = *(const s16x8*)(al1 + kt * 32);
    const size_t boff = (((size_t)kt * 8 + w * 2) * 64 + l) * 8;
    s16x8 Bh0 = *(const s16x8*)(Wchf + boff);
    s16x8 Bh1 = *(const s16x8*)(Wchf + boff + 64 * 8);
    s16x8 Bl0 = *(const s16x8*)(Wclf + boff);
    s16x8 Bl1 = *(const s16x8*)(Wclf + boff + 64 * 8);
    acc[0][0] = __builtin_amdgcn_mfma_f32_16x16x32_bf16(Ah0, Bh0, acc[0][0], 0, 0, 0);
    acc[0][0] = __builtin_amdgcn_mfma_f32_16x16x32_bf16(Al0, Bh0, acc[0][0], 0, 0, 0);
    acc[0][0] = __builtin_amdgcn_mfma_f32_16x16x32_bf16(Ah0, Bl0, acc[0][0], 0, 0, 0);
    acc[0][1] = __builtin_amdgcn_mfma_f32_16x16x32_bf16(Ah0, Bh1, acc[0][1], 0, 0, 0);
    acc[0][1] = __builtin_amdgcn_mfma_f32_16x16x32_bf16(Al0, Bh1, acc[0][1], 0, 0, 0);
    acc[0][1] = __builtin_amdgcn_mfma_f32_16x16x32_bf16(Ah0, Bl1, acc[0][1], 0, 0, 0);
    acc[1][0] = __builtin_amdgcn_mfma_f32_16x16x32_bf16(Ah1, Bh0, acc[1][0], 0, 0, 0);
    acc[1][0] = __builtin_amdgcn_mfma_f32_16x16x32_bf16(Al1, Bh0, acc[1][0], 0, 0, 0);
    acc[1][0] = __builtin_amdgcn_mfma_f32_16x16x32_bf16(Ah1, Bl0, acc[1][0], 0, 0, 0);
    acc[1][1] = __builtin_amdgcn_mfma_f32_16x16x32_bf16(Ah1, Bh1, acc[1][1], 0, 0, 0);
    acc[1][1] = __builtin_amdgcn_mfma_f32_16x16x32_bf16(Al1, Bh1, acc[1][1], 0, 0, 0);
    acc[1][1] = __builtin_amdgcn_mfma_f32_16x16x32_bf16(Ah1, Bl1, acc[1][1], 0, 0, 0);
  }

#pragma unroll
  for (int mi = 0; mi < 2; ++mi)
#pragma unroll
    for (int ni = 0; ni < 2; ++ni)
#pragma unroll
      for (int r = 0; r < 4; ++r) {
        int t  = mi * 16 + q * 4 + r;              // C/D: row=(l>>4)*4+reg
        int es = w * 32 + ni * 16 + r15;
        lg[t * NES + es] = acc[mi][ni][r];
      }
  __syncthreads();

  if (tid < NES) {
    const int es = tid;
    const float bce = bc[es];
    float m1 = -INFINITY, m2 = -INFINITY;
    int am = 0;
    for (int t = 0; t < GT; ++t) {
      float v = (lg[t * NES + es] + bce) + (float)((double)t * (1e-6 / 31.0));
      if (v > m1) { m2 = m1; m1 = v; am = t; }
      else if (v > m2) m2 = v;
    }
    sel[(size_t)g * NES + es] = 1u << am;
    if (!(m1 - m2 > MARGIN_EPS)) {                 // narrow margin (or NaN): exact pass
      unsigned int p = atomicAdd(cnt, 1u);
      flags[p] = ((unsigned int)g << 7) | (unsigned int)es;
    }
  }
}

// ---------------------------------------------------------------------------
// kFix: exact f32 recompute for flagged columns, BIT-IDENTICAL to the r1-r7
// chain (64-dd part flush, dd-sequential fmaf, same tie/max/mask loops).
// ---------------------------------------------------------------------------
__global__ __launch_bounds__(64) void kFix(const float* __restrict__ x,
                                           const float* __restrict__ Wc,
                                           const float* __restrict__ bc,
                                           unsigned int* __restrict__ sel,
                                           const unsigned int* __restrict__ flags,
                                           const unsigned int* __restrict__ cnt) {
  __shared__ float v[GT];
  const int tid = threadIdx.x;
  const unsigned int n = *cnt;
  for (unsigned int i = blockIdx.x; i < n; i += gridDim.x) {
    const unsigned int f = flags[i];
    const int g = (int)(f >> 7), es = (int)(f & 127u);
    if (tid < GT) {
      const float* xr = x + ((size_t)g * GT + tid) * DM;
      const float* wcol = Wc + es;
      float acc = 0.f;
      for (int c = 0; c < 16; ++c) {
        float part = 0.f;
#pragma unroll 4
        for (int s = 0; s < 16; ++s) {
          const int d0 = c * 64 + s * 4;
          float4 xv = *(const float4*)&xr[d0];
          float w0 = wcol[(size_t)(d0 + 0) * NES];
          float w1 = wcol[(size_t)(d0 + 1) * NES];
          float w2 = wcol[(size_t)(d0 + 2) * NES];
          float w3 = wcol[(size_t)(d0 + 3) * NES];
          part = fmaf(xv.x, w0, part);             // dd-sequential (r1 order)
          part = fmaf(xv.y, w1, part);
          part = fmaf(xv.z, w2, part);
          part = fmaf(xv.w, w3, part);
        }
        acc += part;
      }
      v[tid] = (acc + bc[es]) + (float)((double)tid * (1e-6 / 31.0));
    }
    __syncthreads();
    if (tid == 0) {
      float m = -INFINITY;
      for (int t = 0; t < GT; ++t) m = fmaxf(m, v[t]);
      unsigned int msk = 0u;
      for (int t = 0; t < GT; ++t) if (v[t] == m) msk |= (1u << t);
      sel[(size_t)g * NES + es] = msk;
    }
    __syncthreads();
  }
}

// ---------------------------------------------------------------------------
// kBm: inner = relu(xsel . W1[es] + b1[es]) via MFMA (unchanged, proven).
// ---------------------------------------------------------------------------
__global__ __launch_bounds__(256, 2) void kBm(const unsigned short* __restrict__ xb,
                                              const unsigned short* __restrict__ W1f,
                                              const float* __restrict__ b1,
                                              const unsigned int* __restrict__ sel,
                                              unsigned short* __restrict__ innerb) {
  __shared__ unsigned short As[128 * 128];   // [row][k] bf16, byte^((row&7)<<4)
  __shared__ int tokL[128];
  __shared__ unsigned int mulL[128];
  const int bid = blockIdx.x;
  const int es = bid >> 2, g0 = (bid & 3) * 128;
  const int tid = threadIdx.x;
  const int l = tid & 63, w = tid >> 6;
  const int r15 = l & 15, q = l >> 4;
  const int mw = w * 32;

  if (tid < 128) {
    unsigned int m = sel[(size_t)(g0 + tid) * NES + es];
    tokL[tid] = (g0 + tid) * GT + (__ffs(m) - 1);
    mulL[tid] = (m & (m - 1)) ? m : 0u;
  }

  const int r = tid >> 1, p = tid & 1;
  const int swz = (r & 7) << 4;
  const unsigned int dbase = (unsigned int)r * 256 + (unsigned int)p * 128;

  f32x4 acc[2][2];
#pragma unroll
  for (int i = 0; i < 2; ++i)
#pragma unroll
    for (int j = 0; j < 2; ++j) acc[i][j] = (f32x4){0.f, 0.f, 0.f, 0.f};

  for (int c = 0; c < 8; ++c) {
    __syncthreads();
    unsigned int mm = mulL[r];
    if (!mm) {
      const unsigned short* src = xb + (size_t)tokL[r] * DM + c * 128 + p * 64;
#pragma unroll
      for (int j = 0; j < 8; ++j) {
        s16x8 v = *(const s16x8*)(src + j * 8);
        *(s16x8*)((char*)As + ((dbase + j * 16) ^ swz)) = v;
      }
    } else {
      size_t grow = (size_t)(g0 + r) * GT;
#pragma unroll
      for (int j = 0; j < 8; ++j) {
        float av[8] = {0.f, 0.f, 0.f, 0.f, 0.f, 0.f, 0.f, 0.f};
        unsigned int m2 = mm;
        while (m2) {
          int tt = __ffs(m2) - 1; m2 &= m2 - 1;
          s16x8 v = *(const s16x8*)(xb + (grow + tt) * DM + c * 128 + p * 64 + j * 8);
#pragma unroll
          for (int k = 0; k < 8; ++k) av[k] += bf2f((unsigned short)v[k]);
        }
        s16x8 o;
#pragma unroll
        for (int k = 0; k < 8; ++k) o[k] = (short)f2bf(av[k]);
        *(s16x8*)((char*)As + ((dbase + j * 16) ^ swz)) = o;
      }
    }
    __syncthreads();

#pragma unroll
    for (int s = 0; s < 4; ++s) {
      const int ks = c * 4 + s;
      const unsigned short* bp = W1f + ((size_t)es * 32 + ks) * 1024 + l * 8;
      s16x8 bf0 = *(const s16x8*)bp;
      s16x8 bf1 = *(const s16x8*)(bp + 512);
      const int row0 = mw + r15, row1 = mw + 16 + r15;
      s16x8 a0 = *(const s16x8*)((char*)As +
                   (((unsigned)row0 * 256 + s * 64 + q * 16) ^ ((row0 & 7) << 4)));
      s16x8 a1 = *(const s16x8*)((char*)As +
                   (((unsigned)row1 * 256 + s * 64 + q * 16) ^ ((row1 & 7) << 4)));
      acc[0][0] = __builtin_amdgcn_mfma_f32_16x16x32_bf16(a0, bf0, acc[0][0], 0, 0, 0);
      acc[0][1] = __builtin_amdgcn_mfma_f32_16x16x32_bf16(a0, bf1, acc[0][1], 0, 0, 0);
      acc[1][0] = __builtin_amdgcn_mfma_f32_16x16x32_bf16(a1, bf0, acc[1][0], 0, 0, 0);
      acc[1][1] = __builtin_amdgcn_mfma_f32_16x16x32_bf16(a1, bf1, acc[1][1], 0, 0, 0);
    }
  }

  float bia0 = b1[es * FSZ + r15];
  float bia1 = b1[es * FSZ + 16 + r15];
#pragma unroll
  for (int i = 0; i < 2; ++i)
#pragma unroll
    for (int rr = 0; rr < 4; ++rr) {
      int g = g0 + mw + i * 16 + q * 4 + rr;
      unsigned short* op = innerb + ((size_t)es * NGRP + g) * FSZ;
      op[r15]      = f2bf(fmaxf(acc[i][0][rr] + bia0, 0.f));
      op[16 + r15] = f2bf(fmaxf(acc[i][1][rr] + bia1, 0.f));
    }
}

// ---------------------------------------------------------------------------
// kC1: per-es dense GEMM (512g x 32f).(32f x 1024d) -> Rb bf16 [g][Ec][d],
// b2 folded (unchanged, proven).
// ---------------------------------------------------------------------------
__global__ __launch_bounds__(256) void kC1(const unsigned short* __restrict__ innerb,
                                           const unsigned short* __restrict__ W2f,
                                           const float* __restrict__ b2,
                                           unsigned short* __restrict__ Rb,
                                           int es0, int Ec) {
  const int bid = blockIdx.x;
  const int esl = bid >> 5;
  const int es  = es0 + esl;
  const int mt  = (bid >> 3) & 3;
  const int nt  = bid & 7;
  const int tid = threadIdx.x;
  const int l = tid & 63, w = tid >> 6;
  const int r15 = l & 15, q = l >> 4;
  const int g0 = mt * 128 + (w >> 1) * 64;
  const int n0 = nt * 128 + (w & 1) * 64;

  const unsigned short* Ab = innerb + ((size_t)es * NGRP + g0 + r15) * FSZ + q * 8;
  const unsigned short* Bb = W2f + (((size_t)es * 64 + (n0 >> 4)) * 64 + l) * 8;
  s16x8 a[4], b[4];
#pragma unroll
  for (int i = 0; i < 4; ++i) a[i] = *(const s16x8*)(Ab + (size_t)i * 16 * FSZ);
#pragma unroll
  for (int j = 0; j < 4; ++j) b[j] = *(const s16x8*)(Bb + (size_t)j * 64 * 8);

  const f32x4 z = {0.f, 0.f, 0.f, 0.f};
  f32x4 acc[4][4];
#pragma unroll
  for (int i = 0; i < 4; ++i)
#pragma unroll
    for (int j = 0; j < 4; ++j)
      acc[i][j] = __builtin_amdgcn_mfma_f32_16x16x32_bf16(a[i], b[j], z, 0, 0, 0);

#pragma unroll
  for (int j = 0; j < 4; ++j) {
    const int col = n0 + j * 16 + r15;
    const float b2v = b2[(size_t)es * DM + col];
#pragma unroll
    for (int i = 0; i < 4; ++i) {
#pragma unroll
      for (int r = 0; r < 4; ++r) {
        const int g = g0 + i * 16 + q * 4 + r;
        Rb[((size_t)g * Ec + esl) * DM + col] = f2bf(acc[i][j][r] + b2v);
      }
    }
  }
}

// ---------------------------------------------------------------------------
// kC2: per-(group, d-quarter) gather-combine (unchanged, proven).
// ---------------------------------------------------------------------------
__global__ __launch_bounds__(256) void kC2(const unsigned short* __restrict__ Rb,
                                           const unsigned int* __restrict__ sel,
                                           float* __restrict__ out,
                                           int es0, int Ec, int direct) {
  __shared__ unsigned int cnt[32];
  __shared__ unsigned char list[32][128];
  const int bid = blockIdx.x;
  const int g = bid >> 2, dq = bid & 3;
  const int tid = threadIdx.x;
  if (tid < 32) cnt[tid] = 0;
  __syncthreads();
  if (tid < Ec) {
    unsigned int m = sel[(size_t)g * NES + es0 + tid];
    while (m) { int t = __ffs(m) - 1; m &= m - 1;
      unsigned int p = atomicAdd(&cnt[t], 1u);
      list[t][p] = (unsigned char)tid; }
  }
  __syncthreads();
  const int t = tid >> 3, part = tid & 7;
  const int d0 = dq * 256 + part * 32;
  const int n = (int)cnt[t];
  const unsigned short* base = Rb + (size_t)g * Ec * DM + d0;

  float acc[32];
#pragma unroll
  for (int i = 0; i < 32; ++i) acc[i] = 0.f;

  s16x8 cur[4];
  if (n) {
    const unsigned short* r = base + (size_t)list[t][0] * DM;
#pragma unroll
    for (int v = 0; v < 4; ++v) cur[v] = *(const s16x8*)(r + v * 8);
  }
  for (int e = 0; e < n; ++e) {
    s16x8 nxt[4];
    const bool more = (e + 1 < n);
    if (more) {
      const unsigned short* r = base + (size_t)list[t][e + 1] * DM;
#pragma unroll
      for (int v = 0; v < 4; ++v) nxt[v] = *(const s16x8*)(r + v * 8);
    }
#pragma unroll
    for (int v = 0; v < 4; ++v)
#pragma unroll
      for (int k = 0; k < 8; ++k)
        acc[v * 8 + k] += bf2f((unsigned short)cur[v][k]);
    if (more) {
#pragma unroll
      for (int v = 0; v < 4; ++v) cur[v] = nxt[v];
    }
  }

  float* op = out + ((size_t)g * GT + t) * DM + d0;
  if (direct) {
#pragma unroll
    for (int v = 0; v < 8; ++v)
      *(float4*)&op[v * 4] =
          make_float4(acc[v * 4], acc[v * 4 + 1], acc[v * 4 + 2], acc[v * 4 + 3]);
  } else {
#pragma unroll
    for (int v = 0; v < 8; ++v) {
      float4 o = *(float4*)&op[v * 4];
      o.x += acc[v * 4]; o.y += acc[v * 4 + 1];
      o.z += acc[v * 4 + 2]; o.w += acc[v * 4 + 3];
      *(float4*)&op[v * 4] = o;
    }
  }
}

extern "C" void kernel_launch(void* const* d_in, const int* in_sizes, int n_in,
                              void* d_out, int out_size, void* d_ws, size_t ws_size,
                              hipStream_t stream) {
  const float* x  = (const float*)d_in[0];
  const float* Wc = (const float*)d_in[1];
  const float* bc = (const float*)d_in[2];
  const float* W1 = (const float*)d_in[3];
  const float* b1 = (const float*)d_in[4];
  const float* W2 = (const float*)d_in[5];
  const float* b2 = (const float*)d_in[6];
  float* out = (float*)d_out;

  // ws layout (offsets in bytes):
  //   0      sel      256 KB
  //   256K   flags    256 KB (65536 u32, worst-case all columns)
  //   512K   cntr     4 B
  //   768K   Wchf     256 KB
  //   1M     Wclf     256 KB
  //   2M     innerb   4 MB
  //   6M     W2f      8.4 MB
  //   15M    W1f      8.4 MB   (dead after kBm)
  //   24M    xb(=xh)  33.5 MB  (dead after kBm)
  //   60M    xl       33.5 MB  (dead after kLg)
  //   15M    Rb       134 MB   (overlaps W1f/xb/xl: all dead before kC1)
  unsigned int* sel    = (unsigned int*)d_ws;
  unsigned int* flags  = (unsigned int*)((char*)d_ws + (256u << 10));
  unsigned int* cntr   = (unsigned int*)((char*)d_ws + (512u << 10));
  unsigned short* Wchf = (unsigned short*)((char*)d_ws + (768u << 10));
  unsigned short* Wclf = (unsigned short*)((char*)d_ws + (1u << 20));
  unsigned short* innerb = (unsigned short*)((char*)d_ws + (2u << 20));
  unsigned short* W2f  = (unsigned short*)((char*)d_ws + (6u << 20));
  unsigned short* W1f  = (unsigned short*)((char*)d_ws + (15u << 20));
  unsigned short* xb   = (unsigned short*)((char*)d_ws + (24u << 20));
  unsigned short* xl   = (unsigned short*)((char*)d_ws + (60u << 20));
  unsigned short* Rb   = (unsigned short*)((char*)d_ws + (15u << 20));

  int Ec = 128;
  while (Ec > 1 && (15u << 20) + (size_t)NGRP * Ec * DM * 2 > ws_size) Ec >>= 1;
  const int NC = NES / Ec;

  hipMemsetAsync(cntr, 0, 4, stream);
  if (NC > 1)
    hipMemsetAsync(d_out, 0, (size_t)out_size * sizeof(float), stream);
  kSplit<<<8192, 256, 0, stream>>>(x, xb, xl);
  kW<<<4160, 256, 0, stream>>>(W1, W2, Wc, W1f, W2f, Wchf, Wclf);
  kLg<<<NGRP, 256, 0, stream>>>(xb, xl, Wchf, Wclf, bc, sel, flags, cntr);
  kFix<<<1024, 64, 0, stream>>>(x, Wc, bc, sel, flags, cntr);
  kBm<<<NGRP, 256, 0, stream>>>(xb, W1f, b1, sel, innerb);
  for (int c = 0; c < NC; ++c) {
    kC1<<<Ec * 32, 256, 0, stream>>>(innerb, W2f, b2, Rb, c * Ec, Ec);
    kC2<<<NGRP * 4, 256, 0, stream>>>(Rb, sel, out, c * Ec, Ec, NC == 1);
  }
}

// Round 10
// 232.667 us; speedup vs baseline: 1.2462x; 1.0281x over previous
//
#include <hip/hip_runtime.h>
#include <hip/hip_bf16.h>

// BatchSplitFF: DM=1024, NEXPERTS=32, SETS=4 (ES=128 pairs), ESIZE=32, B=2, S=8192
#define DM   1024
#define NES  128
#define GT   32
#define NGRP 512
#define FSZ  32
#define MARGIN_EPS 1e-3f   // > 4x deterministic bound on 3-term bf16-split error

typedef float f32x4 __attribute__((ext_vector_type(4)));
typedef short s16x8 __attribute__((ext_vector_type(8)));

__device__ inline unsigned short f2bf(float f) {   // RNE f32->bf16
  union { float f; unsigned int u; } x; x.f = f;
  unsigned int r = x.u + 0x7fffu + ((x.u >> 16) & 1u);
  return (unsigned short)(r >> 16);
}
__device__ inline float bf2f(unsigned short h) {
  union { unsigned int u; float f; } x; x.u = ((unsigned int)h) << 16;
  return x.f;
}

// ---------------------------------------------------------------------------
// kW: merged weight repack. [0,2048): W1 -> bf16 B-frag (K=d, N=f).
// [2048,4096): W2 -> bf16 B-frag (K=f, N=d). [4096,4160): Wc -> hi/lo bf16
// B-frag (K=d, N=es). Unchanged from r9 (proven).
// ---------------------------------------------------------------------------
__global__ __launch_bounds__(256) void kW(const float* __restrict__ W1,
                                          const float* __restrict__ W2,
                                          const float* __restrict__ Wc,
                                          unsigned short* __restrict__ W1f,
                                          unsigned short* __restrict__ W2f,
                                          unsigned short* __restrict__ Wchf,
                                          unsigned short* __restrict__ Wclf) {
  const int bid = blockIdx.x;
  if (bid < 2048) {
    int idx = bid * 256 + threadIdx.x;             // (es, kt, nh, lane)
    int l = idx & 63, nh = (idx >> 6) & 1, kt = (idx >> 7) & 31, es = idx >> 12;
    const float* src = W1 + ((size_t)es * DM + kt * 32 + (l >> 4) * 8) * FSZ
                          + nh * 16 + (l & 15);
    s16x8 v;
#pragma unroll
    for (int i = 0; i < 8; ++i) v[i] = (short)f2bf(src[(size_t)i * FSZ]);
    *(s16x8*)(W1f + (size_t)idx * 8) = v;
  } else if (bid < 4096) {
    int idx = (bid - 2048) * 256 + threadIdx.x;    // (es, dt, lane)
    int l = idx & 63, dt = (idx >> 6) & 63, es = idx >> 12;
    const float* src = W2 + ((size_t)es * DM + dt * 16 + (l & 15)) * FSZ + (l >> 4) * 8;
    float4 a = *(const float4*)src;
    float4 b = *(const float4*)(src + 4);
    s16x8 v;
    v[0] = (short)f2bf(a.x); v[1] = (short)f2bf(a.y);
    v[2] = (short)f2bf(a.z); v[3] = (short)f2bf(a.w);
    v[4] = (short)f2bf(b.x); v[5] = (short)f2bf(b.y);
    v[6] = (short)f2bf(b.z); v[7] = (short)f2bf(b.w);
    *(s16x8*)(W2f + (size_t)idx * 8) = v;
  } else {
    int idx = (bid - 4096) * 256 + threadIdx.x;    // (kt, nt, lane) in [0,16384)
    int l = idx & 63, nt = (idx >> 6) & 7, kt = idx >> 9;
    const float* src = Wc + (size_t)(kt * 32 + (l >> 4) * 8) * NES + nt * 16 + (l & 15);
    s16x8 h, lo;
#pragma unroll
    for (int i = 0; i < 8; ++i) {
      float v = src[(size_t)i * NES];
      unsigned short hh = f2bf(v);
      h[i]  = (short)hh;
      lo[i] = (short)f2bf(v - bf2f(hh));
    }
    *(s16x8*)(Wchf + (size_t)idx * 8) = h;
    *(s16x8*)(Wclf + (size_t)idx * 8) = lo;
  }
}

// ---------------------------------------------------------------------------
// kLg v2: controller logits via MFMA, hi/lo split FUSED in-register (kSplit
// deleted). Reads x f32 directly (the unavoidable 134 MB), emits xh bf16 for
// kBm as a side product. 8 waves/block: wave (wt = w&1: 16-token m-tile,
// we = w>>1: 32-es n-pair) -> 4 waves/SIMD TLP. MFMA term order per (t,es)
// BIT-IDENTICAL to r9 (hh, lh, hl per kt, kt-sequential) -> identical sel.
// ---------------------------------------------------------------------------
__global__ __launch_bounds__(512, 4) void kLg(const float* __restrict__ x,
                                              const unsigned short* __restrict__ Wchf,
                                              const unsigned short* __restrict__ Wclf,
                                              const float* __restrict__ bc,
                                              unsigned short* __restrict__ xh,
                                              unsigned int* __restrict__ sel,
                                              unsigned int* __restrict__ flags,
                                              unsigned int* __restrict__ cnt) {
  __shared__ float lg[GT * NES];                   // 16 KB
  const int g   = blockIdx.x;
  const int tid = threadIdx.x;
  const int l   = tid & 63, w = tid >> 6;          // 8 waves
  const int wt  = w & 1, we = w >> 1;              // m-tile / es-32-tile
  const int r15 = l & 15, q = l >> 4;
  const int row = g * GT + wt * 16 + r15;
  const float* xrow = x + (size_t)row * DM + q * 8;
  unsigned short* xhrow = xh + (size_t)row * DM + q * 8;

  f32x4 acc0 = {0.f, 0.f, 0.f, 0.f}, acc1 = {0.f, 0.f, 0.f, 0.f};

  for (int kt = 0; kt < 32; ++kt) {
    float4 a = *(const float4*)(xrow + kt * 32);
    float4 b = *(const float4*)(xrow + kt * 32 + 4);
    float v[8] = {a.x, a.y, a.z, a.w, b.x, b.y, b.z, b.w};
    s16x8 Ah, Al;
#pragma unroll
    for (int k = 0; k < 8; ++k) {
      unsigned short h = f2bf(v[k]);
      Ah[k] = (short)h;
      Al[k] = (short)f2bf(v[k] - bf2f(h));
    }
    if (we == 0) *(s16x8*)(xhrow + kt * 32) = Ah;  // xh emission (once/row/kt)

    const size_t b0 = (((size_t)kt * 8 + we * 2) * 64 + l) * 8;
    s16x8 Bh0 = *(const s16x8*)(Wchf + b0);
    s16x8 Bl0 = *(const s16x8*)(Wclf + b0);
    s16x8 Bh1 = *(const s16x8*)(Wchf + b0 + 512);
    s16x8 Bl1 = *(const s16x8*)(Wclf + b0 + 512);
    acc0 = __builtin_amdgcn_mfma_f32_16x16x32_bf16(Ah, Bh0, acc0, 0, 0, 0);
    acc0 = __builtin_amdgcn_mfma_f32_16x16x32_bf16(Al, Bh0, acc0, 0, 0, 0);
    acc0 = __builtin_amdgcn_mfma_f32_16x16x32_bf16(Ah, Bl0, acc0, 0, 0, 0);
    acc1 = __builtin_amdgcn_mfma_f32_16x16x32_bf16(Ah, Bh1, acc1, 0, 0, 0);
    acc1 = __builtin_amdgcn_mfma_f32_16x16x32_bf16(Al, Bh1, acc1, 0, 0, 0);
    acc1 = __builtin_amdgcn_mfma_f32_16x16x32_bf16(Ah, Bl1, acc1, 0, 0, 0);
  }

#pragma unroll
  for (int r = 0; r < 4; ++r) {                    // C/D: row=(l>>4)*4+reg
    const int t = wt * 16 + q * 4 + r;
    lg[t * NES + we * 32 + r15]      = acc0[r];
    lg[t * NES + we * 32 + 16 + r15] = acc1[r];
  }
  __syncthreads();

  if (tid < NES) {                                 // identical to r9 (proven)
    const int es = tid;
    const float bce = bc[es];
    float m1 = -INFINITY, m2 = -INFINITY;
    int am = 0;
    for (int t = 0; t < GT; ++t) {
      float v = (lg[t * NES + es] + bce) + (float)((double)t * (1e-6 / 31.0));
      if (v > m1) { m2 = m1; m1 = v; am = t; }
      else if (v > m2) m2 = v;
    }
    sel[(size_t)g * NES + es] = 1u << am;
    if (!(m1 - m2 > MARGIN_EPS)) {                 // narrow margin (or NaN): exact pass
      unsigned int p = atomicAdd(cnt, 1u);
      flags[p] = ((unsigned int)g << 7) | (unsigned int)es;
    }
  }
}

// ---------------------------------------------------------------------------
// kFix: exact f32 recompute for flagged columns, BIT-IDENTICAL to the r1-r7
// chain (unchanged from r9, proven).
// ---------------------------------------------------------------------------
__global__ __launch_bounds__(64) void kFix(const float* __restrict__ x,
                                           const float* __restrict__ Wc,
                                           const float* __restrict__ bc,
                                           unsigned int* __restrict__ sel,
                                           const unsigned int* __restrict__ flags,
                                           const unsigned int* __restrict__ cnt) {
  __shared__ float v[GT];
  const int tid = threadIdx.x;
  const unsigned int n = *cnt;
  for (unsigned int i = blockIdx.x; i < n; i += gridDim.x) {
    const unsigned int f = flags[i];
    const int g = (int)(f >> 7), es = (int)(f & 127u);
    if (tid < GT) {
      const float* xr = x + ((size_t)g * GT + tid) * DM;
      const float* wcol = Wc + es;
      float acc = 0.f;
      for (int c = 0; c < 16; ++c) {
        float part = 0.f;
#pragma unroll 4
        for (int s = 0; s < 16; ++s) {
          const int d0 = c * 64 + s * 4;
          float4 xv = *(const float4*)&xr[d0];
          float w0 = wcol[(size_t)(d0 + 0) * NES];
          float w1 = wcol[(size_t)(d0 + 1) * NES];
          float w2 = wcol[(size_t)(d0 + 2) * NES];
          float w3 = wcol[(size_t)(d0 + 3) * NES];
          part = fmaf(xv.x, w0, part);             // dd-sequential (r1 order)
          part = fmaf(xv.y, w1, part);
          part = fmaf(xv.z, w2, part);
          part = fmaf(xv.w, w3, part);
        }
        acc += part;
      }
      v[tid] = (acc + bc[es]) + (float)((double)tid * (1e-6 / 31.0));
    }
    __syncthreads();
    if (tid == 0) {
      float m = -INFINITY;
      for (int t = 0; t < GT; ++t) m = fmaxf(m, v[t]);
      unsigned int msk = 0u;
      for (int t = 0; t < GT; ++t) if (v[t] == m) msk |= (1u << t);
      sel[(size_t)g * NES + es] = msk;
    }
    __syncthreads();
  }
}

// ---------------------------------------------------------------------------
// kBm: inner = relu(xsel . W1[es] + b1[es]) via MFMA (unchanged, proven).
// ---------------------------------------------------------------------------
__global__ __launch_bounds__(256, 2) void kBm(const unsigned short* __restrict__ xb,
                                              const unsigned short* __restrict__ W1f,
                                              const float* __restrict__ b1,
                                              const unsigned int* __restrict__ sel,
                                              unsigned short* __restrict__ innerb) {
  __shared__ unsigned short As[128 * 128];   // [row][k] bf16, byte^((row&7)<<4)
  __shared__ int tokL[128];
  __shared__ unsigned int mulL[128];
  const int bid = blockIdx.x;
  const int es = bid >> 2, g0 = (bid & 3) * 128;
  const int tid = threadIdx.x;
  const int l = tid & 63, w = tid >> 6;
  const int r15 = l & 15, q = l >> 4;
  const int mw = w * 32;

  if (tid < 128) {
    unsigned int m = sel[(size_t)(g0 + tid) * NES + es];
    tokL[tid] = (g0 + tid) * GT + (__ffs(m) - 1);
    mulL[tid] = (m & (m - 1)) ? m : 0u;
  }

  const int r = tid >> 1, p = tid & 1;
  const int swz = (r & 7) << 4;
  const unsigned int dbase = (unsigned int)r * 256 + (unsigned int)p * 128;

  f32x4 acc[2][2];
#pragma unroll
  for (int i = 0; i < 2; ++i)
#pragma unroll
    for (int j = 0; j < 2; ++j) acc[i][j] = (f32x4){0.f, 0.f, 0.f, 0.f};

  for (int c = 0; c < 8; ++c) {
    __syncthreads();
    unsigned int mm = mulL[r];
    if (!mm) {
      const unsigned short* src = xb + (size_t)tokL[r] * DM + c * 128 + p * 64;
#pragma unroll
      for (int j = 0; j < 8; ++j) {
        s16x8 v = *(const s16x8*)(src + j * 8);
        *(s16x8*)((char*)As + ((dbase + j * 16) ^ swz)) = v;
      }
    } else {
      size_t grow = (size_t)(g0 + r) * GT;
#pragma unroll
      for (int j = 0; j < 8; ++j) {
        float av[8] = {0.f, 0.f, 0.f, 0.f, 0.f, 0.f, 0.f, 0.f};
        unsigned int m2 = mm;
        while (m2) {
          int tt = __ffs(m2) - 1; m2 &= m2 - 1;
          s16x8 v = *(const s16x8*)(xb + (grow + tt) * DM + c * 128 + p * 64 + j * 8);
#pragma unroll
          for (int k = 0; k < 8; ++k) av[k] += bf2f((unsigned short)v[k]);
        }
        s16x8 o;
#pragma unroll
        for (int k = 0; k < 8; ++k) o[k] = (short)f2bf(av[k]);
        *(s16x8*)((char*)As + ((dbase + j * 16) ^ swz)) = o;
      }
    }
    __syncthreads();

#pragma unroll
    for (int s = 0; s < 4; ++s) {
      const int ks = c * 4 + s;
      const unsigned short* bp = W1f + ((size_t)es * 32 + ks) * 1024 + l * 8;
      s16x8 bf0 = *(const s16x8*)bp;
      s16x8 bf1 = *(const s16x8*)(bp + 512);
      const int row0 = mw + r15, row1 = mw + 16 + r15;
      s16x8 a0 = *(const s16x8*)((char*)As +
                   (((unsigned)row0 * 256 + s * 64 + q * 16) ^ ((row0 & 7) << 4)));
      s16x8 a1 = *(const s16x8*)((char*)As +
                   (((unsigned)row1 * 256 + s * 64 + q * 16) ^ ((row1 & 7) << 4)));
      acc[0][0] = __builtin_amdgcn_mfma_f32_16x16x32_bf16(a0, bf0, acc[0][0], 0, 0, 0);
      acc[0][1] = __builtin_amdgcn_mfma_f32_16x16x32_bf16(a0, bf1, acc[0][1], 0, 0, 0);
      acc[1][0] = __builtin_amdgcn_mfma_f32_16x16x32_bf16(a1, bf0, acc[1][0], 0, 0, 0);
      acc[1][1] = __builtin_amdgcn_mfma_f32_16x16x32_bf16(a1, bf1, acc[1][1], 0, 0, 0);
    }
  }

  float bia0 = b1[es * FSZ + r15];
  float bia1 = b1[es * FSZ + 16 + r15];
#pragma unroll
  for (int i = 0; i < 2; ++i)
#pragma unroll
    for (int rr = 0; rr < 4; ++rr) {
      int g = g0 + mw + i * 16 + q * 4 + rr;
      unsigned short* op = innerb + ((size_t)es * NGRP + g) * FSZ;
      op[r15]      = f2bf(fmaxf(acc[i][0][rr] + bia0, 0.f));
      op[16 + r15] = f2bf(fmaxf(acc[i][1][rr] + bia1, 0.f));
    }
}

// ---------------------------------------------------------------------------
// kC1: per-es dense GEMM (512g x 32f).(32f x 1024d) -> Rb bf16 [g][Ec][d],
// b2 folded (unchanged, proven).
// ---------------------------------------------------------------------------
__global__ __launch_bounds__(256) void kC1(const unsigned short* __restrict__ innerb,
                                           const unsigned short* __restrict__ W2f,
                                           const float* __restrict__ b2,
                                           unsigned short* __restrict__ Rb,
                                           int es0, int Ec) {
  const int bid = blockIdx.x;
  const int esl = bid >> 5;
  const int es  = es0 + esl;
  const int mt  = (bid >> 3) & 3;
  const int nt  = bid & 7;
  const int tid = threadIdx.x;
  const int l = tid & 63, w = tid >> 6;
  const int r15 = l & 15, q = l >> 4;
  const int g0 = mt * 128 + (w >> 1) * 64;
  const int n0 = nt * 128 + (w & 1) * 64;

  const unsigned short* Ab = innerb + ((size_t)es * NGRP + g0 + r15) * FSZ + q * 8;
  const unsigned short* Bb = W2f + (((size_t)es * 64 + (n0 >> 4)) * 64 + l) * 8;
  s16x8 a[4], b[4];
#pragma unroll
  for (int i = 0; i < 4; ++i) a[i] = *(const s16x8*)(Ab + (size_t)i * 16 * FSZ);
#pragma unroll
  for (int j = 0; j < 4; ++j) b[j] = *(const s16x8*)(Bb + (size_t)j * 64 * 8);

  const f32x4 z = {0.f, 0.f, 0.f, 0.f};
  f32x4 acc[4][4];
#pragma unroll
  for (int i = 0; i < 4; ++i)
#pragma unroll
    for (int j = 0; j < 4; ++j)
      acc[i][j] = __builtin_amdgcn_mfma_f32_16x16x32_bf16(a[i], b[j], z, 0, 0, 0);

#pragma unroll
  for (int j = 0; j < 4; ++j) {
    const int col = n0 + j * 16 + r15;
    const float b2v = b2[(size_t)es * DM + col];
#pragma unroll
    for (int i = 0; i < 4; ++i) {
#pragma unroll
      for (int r = 0; r < 4; ++r) {
        const int g = g0 + i * 16 + q * 4 + r;
        Rb[((size_t)g * Ec + esl) * DM + col] = f2bf(acc[i][j][r] + b2v);
      }
    }
  }
}

// ---------------------------------------------------------------------------
// kC2: per-(group, d-quarter) gather-combine (unchanged, proven).
// ---------------------------------------------------------------------------
__global__ __launch_bounds__(256) void kC2(const unsigned short* __restrict__ Rb,
                                           const unsigned int* __restrict__ sel,
                                           float* __restrict__ out,
                                           int es0, int Ec, int direct) {
  __shared__ unsigned int cnt[32];
  __shared__ unsigned char list[32][128];
  const int bid = blockIdx.x;
  const int g = bid >> 2, dq = bid & 3;
  const int tid = threadIdx.x;
  if (tid < 32) cnt[tid] = 0;
  __syncthreads();
  if (tid < Ec) {
    unsigned int m = sel[(size_t)g * NES + es0 + tid];
    while (m) { int t = __ffs(m) - 1; m &= m - 1;
      unsigned int p = atomicAdd(&cnt[t], 1u);
      list[t][p] = (unsigned char)tid; }
  }
  __syncthreads();
  const int t = tid >> 3, part = tid & 7;
  const int d0 = dq * 256 + part * 32;
  const int n = (int)cnt[t];
  const unsigned short* base = Rb + (size_t)g * Ec * DM + d0;

  float acc[32];
#pragma unroll
  for (int i = 0; i < 32; ++i) acc[i] = 0.f;

  s16x8 cur[4];
  if (n) {
    const unsigned short* r = base + (size_t)list[t][0] * DM;
#pragma unroll
    for (int v = 0; v < 4; ++v) cur[v] = *(const s16x8*)(r + v * 8);
  }
  for (int e = 0; e < n; ++e) {
    s16x8 nxt[4];
    const bool more = (e + 1 < n);
    if (more) {
      const unsigned short* r = base + (size_t)list[t][e + 1] * DM;
#pragma unroll
      for (int v = 0; v < 4; ++v) nxt[v] = *(const s16x8*)(r + v * 8);
    }
#pragma unroll
    for (int v = 0; v < 4; ++v)
#pragma unroll
      for (int k = 0; k < 8; ++k)
        acc[v * 8 + k] += bf2f((unsigned short)cur[v][k]);
    if (more) {
#pragma unroll
      for (int v = 0; v < 4; ++v) cur[v] = nxt[v];
    }
  }

  float* op = out + ((size_t)g * GT + t) * DM + d0;
  if (direct) {
#pragma unroll
    for (int v = 0; v < 8; ++v)
      *(float4*)&op[v * 4] =
          make_float4(acc[v * 4], acc[v * 4 + 1], acc[v * 4 + 2], acc[v * 4 + 3]);
  } else {
#pragma unroll
    for (int v = 0; v < 8; ++v) {
      float4 o = *(float4*)&op[v * 4];
      o.x += acc[v * 4]; o.y += acc[v * 4 + 1];
      o.z += acc[v * 4 + 2]; o.w += acc[v * 4 + 3];
      *(float4*)&op[v * 4] = o;
    }
  }
}

extern "C" void kernel_launch(void* const* d_in, const int* in_sizes, int n_in,
                              void* d_out, int out_size, void* d_ws, size_t ws_size,
                              hipStream_t stream) {
  const float* x  = (const float*)d_in[0];
  const float* Wc = (const float*)d_in[1];
  const float* bc = (const float*)d_in[2];
  const float* W1 = (const float*)d_in[3];
  const float* b1 = (const float*)d_in[4];
  const float* W2 = (const float*)d_in[5];
  const float* b2 = (const float*)d_in[6];
  float* out = (float*)d_out;

  // ws layout (offsets in bytes):
  //   0      sel      256 KB
  //   256K   flags    256 KB (65536 u32, worst-case all columns)
  //   512K   cntr     4 B
  //   768K   Wchf     256 KB
  //   1M     Wclf     256 KB
  //   2M     innerb   4 MB
  //   6M     W2f      8.4 MB
  //   15M    W1f      8.4 MB   (dead after kBm)
  //   24M    xb(=xh)  33.5 MB  (dead after kBm)
  //   15M    Rb       134 MB   (overlaps W1f/xb: both dead before kC1)
  unsigned int* sel    = (unsigned int*)d_ws;
  unsigned int* flags  = (unsigned int*)((char*)d_ws + (256u << 10));
  unsigned int* cntr   = (unsigned int*)((char*)d_ws + (512u << 10));
  unsigned short* Wchf = (unsigned short*)((char*)d_ws + (768u << 10));
  unsigned short* Wclf = (unsigned short*)((char*)d_ws + (1u << 20));
  unsigned short* innerb = (unsigned short*)((char*)d_ws + (2u << 20));
  unsigned short* W2f  = (unsigned short*)((char*)d_ws + (6u << 20));
  unsigned short* W1f  = (unsigned short*)((char*)d_ws + (15u << 20));
  unsigned short* xb   = (unsigned short*)((char*)d_ws + (24u << 20));
  unsigned short* Rb   = (unsigned short*)((char*)d_ws + (15u << 20));

  int Ec = 128;
  while (Ec > 1 && (15u << 20) + (size_t)NGRP * Ec * DM * 2 > ws_size) Ec >>= 1;
  const int NC = NES / Ec;

  hipMemsetAsync(cntr, 0, 4, stream);
  if (NC > 1)
    hipMemsetAsync(d_out, 0, (size_t)out_size * sizeof(float), stream);
  kW<<<4160, 256, 0, stream>>>(W1, W2, Wc, W1f, W2f, Wchf, Wclf);
  kLg<<<NGRP, 512, 0, stream>>>(x, Wchf, Wclf, bc, xb, sel, flags, cntr);
  kFix<<<1024, 64, 0, stream>>>(x, Wc, bc, sel, flags, cntr);
  kBm<<<NGRP, 256, 0, stream>>>(xb, W1f, b1, sel, innerb);
  for (int c = 0; c < NC; ++c) {
    kC1<<<Ec * 32, 256, 0, stream>>>(innerb, W2f, b2, Rb, c * Ec, Ec);
    kC2<<<NGRP * 4, 256, 0, stream>>>(Rb, sel, out, c * Ec, Ec, NC == 1);
  }
}

// Round 11
// 230.686 us; speedup vs baseline: 1.2569x; 1.0086x over previous
//
#include <hip/hip_runtime.h>
#include <hip/hip_bf16.h>

// BatchSplitFF: DM=1024, NEXPERTS=32, SETS=4 (ES=128 pairs), ESIZE=32, B=2, S=8192
#define DM   1024
#define NES  128
#define GT   32
#define NGRP 512
#define FSZ  32
#define MARGIN_EPS 1e-3f   // > 4x deterministic bound on 3-term bf16-split error

typedef float f32x4 __attribute__((ext_vector_type(4)));
typedef short s16x8 __attribute__((ext_vector_type(8)));

__device__ inline unsigned short f2bf(float f) {   // RNE f32->bf16
  union { float f; unsigned int u; } x; x.f = f;
  unsigned int r = x.u + 0x7fffu + ((x.u >> 16) & 1u);
  return (unsigned short)(r >> 16);
}
__device__ inline float bf2f(unsigned short h) {
  union { unsigned int u; float f; } x; x.u = ((unsigned int)h) << 16;
  return x.f;
}

// ---------------------------------------------------------------------------
// kW: merged weight repack. [0,2048): W1 -> bf16 B-frag (K=d, N=f).
// [2048,4096): W2 -> bf16 B-frag (K=f, N=d). [4096,4160): Wc -> hi/lo bf16
// B-frag (K=d, N=es). Unchanged (proven).
// ---------------------------------------------------------------------------
__global__ __launch_bounds__(256) void kW(const float* __restrict__ W1,
                                          const float* __restrict__ W2,
                                          const float* __restrict__ Wc,
                                          unsigned short* __restrict__ W1f,
                                          unsigned short* __restrict__ W2f,
                                          unsigned short* __restrict__ Wchf,
                                          unsigned short* __restrict__ Wclf) {
  const int bid = blockIdx.x;
  if (bid < 2048) {
    int idx = bid * 256 + threadIdx.x;             // (es, kt, nh, lane)
    int l = idx & 63, nh = (idx >> 6) & 1, kt = (idx >> 7) & 31, es = idx >> 12;
    const float* src = W1 + ((size_t)es * DM + kt * 32 + (l >> 4) * 8) * FSZ
                          + nh * 16 + (l & 15);
    s16x8 v;
#pragma unroll
    for (int i = 0; i < 8; ++i) v[i] = (short)f2bf(src[(size_t)i * FSZ]);
    *(s16x8*)(W1f + (size_t)idx * 8) = v;
  } else if (bid < 4096) {
    int idx = (bid - 2048) * 256 + threadIdx.x;    // (es, dt, lane)
    int l = idx & 63, dt = (idx >> 6) & 63, es = idx >> 12;
    const float* src = W2 + ((size_t)es * DM + dt * 16 + (l & 15)) * FSZ + (l >> 4) * 8;
    float4 a = *(const float4*)src;
    float4 b = *(const float4*)(src + 4);
    s16x8 v;
    v[0] = (short)f2bf(a.x); v[1] = (short)f2bf(a.y);
    v[2] = (short)f2bf(a.z); v[3] = (short)f2bf(a.w);
    v[4] = (short)f2bf(b.x); v[5] = (short)f2bf(b.y);
    v[6] = (short)f2bf(b.z); v[7] = (short)f2bf(b.w);
    *(s16x8*)(W2f + (size_t)idx * 8) = v;
  } else {
    int idx = (bid - 4096) * 256 + threadIdx.x;    // (kt, nt, lane) in [0,16384)
    int l = idx & 63, nt = (idx >> 6) & 7, kt = idx >> 9;
    const float* src = Wc + (size_t)(kt * 32 + (l >> 4) * 8) * NES + nt * 16 + (l & 15);
    s16x8 h, lo;
#pragma unroll
    for (int i = 0; i < 8; ++i) {
      float v = src[(size_t)i * NES];
      unsigned short hh = f2bf(v);
      h[i]  = (short)hh;
      lo[i] = (short)f2bf(v - bf2f(hh));
    }
    *(s16x8*)(Wchf + (size_t)idx * 8) = h;
    *(s16x8*)(Wclf + (size_t)idx * 8) = lo;
  }
}

// ---------------------------------------------------------------------------
// kLg v3: same math as v2 (fused hi/lo split, MFMA term order BIT-IDENTICAL:
// hh, lh, hl per kt, kt-sequential), but with an EXPLICIT depth-1 register
// pipeline: next-kt x + B-frags are loaded at the top of each iteration and
// consumed one body later. v2's VGPR_Count=28 showed the compiler serialized
// every load->use; named slots force overlap. ~76 VGPR (< 128 => 16 waves/CU).
// ---------------------------------------------------------------------------
__global__ __launch_bounds__(512, 4) void kLg(const float* __restrict__ x,
                                              const unsigned short* __restrict__ Wchf,
                                              const unsigned short* __restrict__ Wclf,
                                              const float* __restrict__ bc,
                                              unsigned short* __restrict__ xh,
                                              unsigned int* __restrict__ sel,
                                              unsigned int* __restrict__ flags,
                                              unsigned int* __restrict__ cnt) {
  __shared__ float lg[GT * NES];                   // 16 KB
  const int g   = blockIdx.x;
  const int tid = threadIdx.x;
  const int l   = tid & 63, w = tid >> 6;          // 8 waves
  const int wt  = w & 1, we = w >> 1;              // m-tile / es-32-tile
  const int r15 = l & 15, q = l >> 4;
  const int row = g * GT + wt * 16 + r15;
  const float* xrow = x + (size_t)row * DM + q * 8;
  unsigned short* xhrow = xh + (size_t)row * DM + q * 8;
  const unsigned short* Bh_base = Wchf + ((size_t)(we * 2) * 64 + l) * 8;
  const unsigned short* Bl_base = Wclf + ((size_t)(we * 2) * 64 + l) * 8;
  // per-kt stride in shorts: 8 frag-groups * 64 lanes * 8 = 4096

  f32x4 acc0 = {0.f, 0.f, 0.f, 0.f}, acc1 = {0.f, 0.f, 0.f, 0.f};

  // pipeline slots (current / next)
  float4 xa = *(const float4*)(xrow);
  float4 xb4 = *(const float4*)(xrow + 4);
  s16x8 Bh0 = *(const s16x8*)(Bh_base);
  s16x8 Bl0 = *(const s16x8*)(Bl_base);
  s16x8 Bh1 = *(const s16x8*)(Bh_base + 512);
  s16x8 Bl1 = *(const s16x8*)(Bl_base + 512);

  for (int kt = 0; kt < 32; ++kt) {
    const int ktn = (kt < 31) ? kt + 1 : 31;       // clamped (last iter dummy)
    // --- issue next-kt loads (consumed one body later) ---
    float4 nxa = *(const float4*)(xrow + ktn * 32);
    float4 nxb = *(const float4*)(xrow + ktn * 32 + 4);
    const unsigned short* nbh = Bh_base + (size_t)ktn * 4096;
    const unsigned short* nbl = Bl_base + (size_t)ktn * 4096;
    s16x8 nBh0 = *(const s16x8*)(nbh);
    s16x8 nBl0 = *(const s16x8*)(nbl);
    s16x8 nBh1 = *(const s16x8*)(nbh + 512);
    s16x8 nBl1 = *(const s16x8*)(nbl + 512);

    // --- convert current x slab to hi/lo bf16 ---
    float v[8] = {xa.x, xa.y, xa.z, xa.w, xb4.x, xb4.y, xb4.z, xb4.w};
    s16x8 Ah, Al;
#pragma unroll
    for (int k = 0; k < 8; ++k) {
      unsigned short h = f2bf(v[k]);
      Ah[k] = (short)h;
      Al[k] = (short)f2bf(v[k] - bf2f(h));
    }
    if (we == 0) *(s16x8*)(xhrow + kt * 32) = Ah;  // xh emission (once/row/kt)

    // --- MFMA: hh, lh, hl per accumulator (r9/r10 order, proven) ---
    acc0 = __builtin_amdgcn_mfma_f32_16x16x32_bf16(Ah, Bh0, acc0, 0, 0, 0);
    acc0 = __builtin_amdgcn_mfma_f32_16x16x32_bf16(Al, Bh0, acc0, 0, 0, 0);
    acc0 = __builtin_amdgcn_mfma_f32_16x16x32_bf16(Ah, Bl0, acc0, 0, 0, 0);
    acc1 = __builtin_amdgcn_mfma_f32_16x16x32_bf16(Ah, Bh1, acc1, 0, 0, 0);
    acc1 = __builtin_amdgcn_mfma_f32_16x16x32_bf16(Al, Bh1, acc1, 0, 0, 0);
    acc1 = __builtin_amdgcn_mfma_f32_16x16x32_bf16(Ah, Bl1, acc1, 0, 0, 0);

    // --- rotate pipeline ---
    xa = nxa; xb4 = nxb;
    Bh0 = nBh0; Bl0 = nBl0; Bh1 = nBh1; Bl1 = nBl1;
  }

#pragma unroll
  for (int r = 0; r < 4; ++r) {                    // C/D: row=(l>>4)*4+reg
    const int t = wt * 16 + q * 4 + r;
    lg[t * NES + we * 32 + r15]      = acc0[r];
    lg[t * NES + we * 32 + 16 + r15] = acc1[r];
  }
  __syncthreads();

  if (tid < NES) {                                 // identical to r9/r10 (proven)
    const int es = tid;
    const float bce = bc[es];
    float m1 = -INFINITY, m2 = -INFINITY;
    int am = 0;
    for (int t = 0; t < GT; ++t) {
      float v = (lg[t * NES + es] + bce) + (float)((double)t * (1e-6 / 31.0));
      if (v > m1) { m2 = m1; m1 = v; am = t; }
      else if (v > m2) m2 = v;
    }
    sel[(size_t)g * NES + es] = 1u << am;
    if (!(m1 - m2 > MARGIN_EPS)) {                 // narrow margin (or NaN): exact pass
      unsigned int p = atomicAdd(cnt, 1u);
      flags[p] = ((unsigned int)g << 7) | (unsigned int)es;
    }
  }
}

// ---------------------------------------------------------------------------
// kFix: exact f32 recompute for flagged columns, BIT-IDENTICAL to the r1-r7
// chain (unchanged, proven).
// ---------------------------------------------------------------------------
__global__ __launch_bounds__(64) void kFix(const float* __restrict__ x,
                                           const float* __restrict__ Wc,
                                           const float* __restrict__ bc,
                                           unsigned int* __restrict__ sel,
                                           const unsigned int* __restrict__ flags,
                                           const unsigned int* __restrict__ cnt) {
  __shared__ float v[GT];
  const int tid = threadIdx.x;
  const unsigned int n = *cnt;
  for (unsigned int i = blockIdx.x; i < n; i += gridDim.x) {
    const unsigned int f = flags[i];
    const int g = (int)(f >> 7), es = (int)(f & 127u);
    if (tid < GT) {
      const float* xr = x + ((size_t)g * GT + tid) * DM;
      const float* wcol = Wc + es;
      float acc = 0.f;
      for (int c = 0; c < 16; ++c) {
        float part = 0.f;
#pragma unroll 4
        for (int s = 0; s < 16; ++s) {
          const int d0 = c * 64 + s * 4;
          float4 xv = *(const float4*)&xr[d0];
          float w0 = wcol[(size_t)(d0 + 0) * NES];
          float w1 = wcol[(size_t)(d0 + 1) * NES];
          float w2 = wcol[(size_t)(d0 + 2) * NES];
          float w3 = wcol[(size_t)(d0 + 3) * NES];
          part = fmaf(xv.x, w0, part);             // dd-sequential (r1 order)
          part = fmaf(xv.y, w1, part);
          part = fmaf(xv.z, w2, part);
          part = fmaf(xv.w, w3, part);
        }
        acc += part;
      }
      v[tid] = (acc + bc[es]) + (float)((double)tid * (1e-6 / 31.0));
    }
    __syncthreads();
    if (tid == 0) {
      float m = -INFINITY;
      for (int t = 0; t < GT; ++t) m = fmaxf(m, v[t]);
      unsigned int msk = 0u;
      for (int t = 0; t < GT; ++t) if (v[t] == m) msk |= (1u << t);
      sel[(size_t)g * NES + es] = msk;
    }
    __syncthreads();
  }
}

// ---------------------------------------------------------------------------
// kBm: inner = relu(xsel . W1[es] + b1[es]) via MFMA (unchanged, proven).
// ---------------------------------------------------------------------------
__global__ __launch_bounds__(256, 2) void kBm(const unsigned short* __restrict__ xb,
                                              const unsigned short* __restrict__ W1f,
                                              const float* __restrict__ b1,
                                              const unsigned int* __restrict__ sel,
                                              unsigned short* __restrict__ innerb) {
  __shared__ unsigned short As[128 * 128];   // [row][k] bf16, byte^((row&7)<<4)
  __shared__ int tokL[128];
  __shared__ unsigned int mulL[128];
  const int bid = blockIdx.x;
  const int es = bid >> 2, g0 = (bid & 3) * 128;
  const int tid = threadIdx.x;
  const int l = tid & 63, w = tid >> 6;
  const int r15 = l & 15, q = l >> 4;
  const int mw = w * 32;

  if (tid < 128) {
    unsigned int m = sel[(size_t)(g0 + tid) * NES + es];
    tokL[tid] = (g0 + tid) * GT + (__ffs(m) - 1);
    mulL[tid] = (m & (m - 1)) ? m : 0u;
  }

  const int r = tid >> 1, p = tid & 1;
  const int swz = (r & 7) << 4;
  const unsigned int dbase = (unsigned int)r * 256 + (unsigned int)p * 128;

  f32x4 acc[2][2];
#pragma unroll
  for (int i = 0; i < 2; ++i)
#pragma unroll
    for (int j = 0; j < 2; ++j) acc[i][j] = (f32x4){0.f, 0.f, 0.f, 0.f};

  for (int c = 0; c < 8; ++c) {
    __syncthreads();
    unsigned int mm = mulL[r];
    if (!mm) {
      const unsigned short* src = xb + (size_t)tokL[r] * DM + c * 128 + p * 64;
#pragma unroll
      for (int j = 0; j < 8; ++j) {
        s16x8 v = *(const s16x8*)(src + j * 8);
        *(s16x8*)((char*)As + ((dbase + j * 16) ^ swz)) = v;
      }
    } else {
      size_t grow = (size_t)(g0 + r) * GT;
#pragma unroll
      for (int j = 0; j < 8; ++j) {
        float av[8] = {0.f, 0.f, 0.f, 0.f, 0.f, 0.f, 0.f, 0.f};
        unsigned int m2 = mm;
        while (m2) {
          int tt = __ffs(m2) - 1; m2 &= m2 - 1;
          s16x8 v = *(const s16x8*)(xb + (grow + tt) * DM + c * 128 + p * 64 + j * 8);
#pragma unroll
          for (int k = 0; k < 8; ++k) av[k] += bf2f((unsigned short)v[k]);
        }
        s16x8 o;
#pragma unroll
        for (int k = 0; k < 8; ++k) o[k] = (short)f2bf(av[k]);
        *(s16x8*)((char*)As + ((dbase + j * 16) ^ swz)) = o;
      }
    }
    __syncthreads();

#pragma unroll
    for (int s = 0; s < 4; ++s) {
      const int ks = c * 4 + s;
      const unsigned short* bp = W1f + ((size_t)es * 32 + ks) * 1024 + l * 8;
      s16x8 bf0 = *(const s16x8*)bp;
      s16x8 bf1 = *(const s16x8*)(bp + 512);
      const int row0 = mw + r15, row1 = mw + 16 + r15;
      s16x8 a0 = *(const s16x8*)((char*)As +
                   (((unsigned)row0 * 256 + s * 64 + q * 16) ^ ((row0 & 7) << 4)));
      s16x8 a1 = *(const s16x8*)((char*)As +
                   (((unsigned)row1 * 256 + s * 64 + q * 16) ^ ((row1 & 7) << 4)));
      acc[0][0] = __builtin_amdgcn_mfma_f32_16x16x32_bf16(a0, bf0, acc[0][0], 0, 0, 0);
      acc[0][1] = __builtin_amdgcn_mfma_f32_16x16x32_bf16(a0, bf1, acc[0][1], 0, 0, 0);
      acc[1][0] = __builtin_amdgcn_mfma_f32_16x16x32_bf16(a1, bf0, acc[1][0], 0, 0, 0);
      acc[1][1] = __builtin_amdgcn_mfma_f32_16x16x32_bf16(a1, bf1, acc[1][1], 0, 0, 0);
    }
  }

  float bia0 = b1[es * FSZ + r15];
  float bia1 = b1[es * FSZ + 16 + r15];
#pragma unroll
  for (int i = 0; i < 2; ++i)
#pragma unroll
    for (int rr = 0; rr < 4; ++rr) {
      int g = g0 + mw + i * 16 + q * 4 + rr;
      unsigned short* op = innerb + ((size_t)es * NGRP + g) * FSZ;
      op[r15]      = f2bf(fmaxf(acc[i][0][rr] + bia0, 0.f));
      op[16 + r15] = f2bf(fmaxf(acc[i][1][rr] + bia1, 0.f));
    }
}

// ---------------------------------------------------------------------------
// kC1: per-es dense GEMM (512g x 32f).(32f x 1024d) -> Rb bf16 [g][Ec][d],
// b2 folded (unchanged, proven).
// ---------------------------------------------------------------------------
__global__ __launch_bounds__(256) void kC1(const unsigned short* __restrict__ innerb,
                                           const unsigned short* __restrict__ W2f,
                                           const float* __restrict__ b2,
                                           unsigned short* __restrict__ Rb,
                                           int es0, int Ec) {
  const int bid = blockIdx.x;
  const int esl = bid >> 5;
  const int es  = es0 + esl;
  const int mt  = (bid >> 3) & 3;
  const int nt  = bid & 7;
  const int tid = threadIdx.x;
  const int l = tid & 63, w = tid >> 6;
  const int r15 = l & 15, q = l >> 4;
  const int g0 = mt * 128 + (w >> 1) * 64;
  const int n0 = nt * 128 + (w & 1) * 64;

  const unsigned short* Ab = innerb + ((size_t)es * NGRP + g0 + r15) * FSZ + q * 8;
  const unsigned short* Bb = W2f + (((size_t)es * 64 + (n0 >> 4)) * 64 + l) * 8;
  s16x8 a[4], b[4];
#pragma unroll
  for (int i = 0; i < 4; ++i) a[i] = *(const s16x8*)(Ab + (size_t)i * 16 * FSZ);
#pragma unroll
  for (int j = 0; j < 4; ++j) b[j] = *(const s16x8*)(Bb + (size_t)j * 64 * 8);

  const f32x4 z = {0.f, 0.f, 0.f, 0.f};
  f32x4 acc[4][4];
#pragma unroll
  for (int i = 0; i < 4; ++i)
#pragma unroll
    for (int j = 0; j < 4; ++j)
      acc[i][j] = __builtin_amdgcn_mfma_f32_16x16x32_bf16(a[i], b[j], z, 0, 0, 0);

#pragma unroll
  for (int j = 0; j < 4; ++j) {
    const int col = n0 + j * 16 + r15;
    const float b2v = b2[(size_t)es * DM + col];
#pragma unroll
    for (int i = 0; i < 4; ++i) {
#pragma unroll
      for (int r = 0; r < 4; ++r) {
        const int g = g0 + i * 16 + q * 4 + r;
        Rb[((size_t)g * Ec + esl) * DM + col] = f2bf(acc[i][j][r] + b2v);
      }
    }
  }
}

// ---------------------------------------------------------------------------
// kC2: per-(group, d-quarter) gather-combine (unchanged, proven).
// ---------------------------------------------------------------------------
__global__ __launch_bounds__(256) void kC2(const unsigned short* __restrict__ Rb,
                                           const unsigned int* __restrict__ sel,
                                           float* __restrict__ out,
                                           int es0, int Ec, int direct) {
  __shared__ unsigned int cnt[32];
  __shared__ unsigned char list[32][128];
  const int bid = blockIdx.x;
  const int g = bid >> 2, dq = bid & 3;
  const int tid = threadIdx.x;
  if (tid < 32) cnt[tid] = 0;
  __syncthreads();
  if (tid < Ec) {
    unsigned int m = sel[(size_t)g * NES + es0 + tid];
    while (m) { int t = __ffs(m) - 1; m &= m - 1;
      unsigned int p = atomicAdd(&cnt[t], 1u);
      list[t][p] = (unsigned char)tid; }
  }
  __syncthreads();
  const int t = tid >> 3, part = tid & 7;
  const int d0 = dq * 256 + part * 32;
  const int n = (int)cnt[t];
  const unsigned short* base = Rb + (size_t)g * Ec * DM + d0;

  float acc[32];
#pragma unroll
  for (int i = 0; i < 32; ++i) acc[i] = 0.f;

  s16x8 cur[4];
  if (n) {
    const unsigned short* r = base + (size_t)list[t][0] * DM;
#pragma unroll
    for (int v = 0; v < 4; ++v) cur[v] = *(const s16x8*)(r + v * 8);
  }
  for (int e = 0; e < n; ++e) {
    s16x8 nxt[4];
    const bool more = (e + 1 < n);
    if (more) {
      const unsigned short* r = base + (size_t)list[t][e + 1] * DM;
#pragma unroll
      for (int v = 0; v < 4; ++v) nxt[v] = *(const s16x8*)(r + v * 8);
    }
#pragma unroll
    for (int v = 0; v < 4; ++v)
#pragma unroll
      for (int k = 0; k < 8; ++k)
        acc[v * 8 + k] += bf2f((unsigned short)cur[v][k]);
    if (more) {
#pragma unroll
      for (int v = 0; v < 4; ++v) cur[v] = nxt[v];
    }
  }

  float* op = out + ((size_t)g * GT + t) * DM + d0;
  if (direct) {
#pragma unroll
    for (int v = 0; v < 8; ++v)
      *(float4*)&op[v * 4] =
          make_float4(acc[v * 4], acc[v * 4 + 1], acc[v * 4 + 2], acc[v * 4 + 3]);
  } else {
#pragma unroll
    for (int v = 0; v < 8; ++v) {
      float4 o = *(float4*)&op[v * 4];
      o.x += acc[v * 4]; o.y += acc[v * 4 + 1];
      o.z += acc[v * 4 + 2]; o.w += acc[v * 4 + 3];
      *(float4*)&op[v * 4] = o;
    }
  }
}

extern "C" void kernel_launch(void* const* d_in, const int* in_sizes, int n_in,
                              void* d_out, int out_size, void* d_ws, size_t ws_size,
                              hipStream_t stream) {
  const float* x  = (const float*)d_in[0];
  const float* Wc = (const float*)d_in[1];
  const float* bc = (const float*)d_in[2];
  const float* W1 = (const float*)d_in[3];
  const float* b1 = (const float*)d_in[4];
  const float* W2 = (const float*)d_in[5];
  const float* b2 = (const float*)d_in[6];
  float* out = (float*)d_out;

  // ws layout (offsets in bytes):
  //   0      sel      256 KB
  //   256K   flags    256 KB (65536 u32, worst-case all columns)
  //   512K   cntr     4 B
  //   768K   Wchf     256 KB
  //   1M     Wclf     256 KB
  //   2M     innerb   4 MB
  //   6M     W2f      8.4 MB
  //   15M    W1f      8.4 MB   (dead after kBm)
  //   24M    xb(=xh)  33.5 MB  (dead after kBm)
  //   15M    Rb       134 MB   (overlaps W1f/xb: both dead before kC1)
  unsigned int* sel    = (unsigned int*)d_ws;
  unsigned int* flags  = (unsigned int*)((char*)d_ws + (256u << 10));
  unsigned int* cntr   = (unsigned int*)((char*)d_ws + (512u << 10));
  unsigned short* Wchf = (unsigned short*)((char*)d_ws + (768u << 10));
  unsigned short* Wclf = (unsigned short*)((char*)d_ws + (1u << 20));
  unsigned short* innerb = (unsigned short*)((char*)d_ws + (2u << 20));
  unsigned short* W2f  = (unsigned short*)((char*)d_ws + (6u << 20));
  unsigned short* W1f  = (unsigned short*)((char*)d_ws + (15u << 20));
  unsigned short* xb   = (unsigned short*)((char*)d_ws + (24u << 20));
  unsigned short* Rb   = (unsigned short*)((char*)d_ws + (15u << 20));

  int Ec = 128;
  while (Ec > 1 && (15u << 20) + (size_t)NGRP * Ec * DM * 2 > ws_size) Ec >>= 1;
  const int NC = NES / Ec;

  hipMemsetAsync(cntr, 0, 4, stream);
  if (NC > 1)
    hipMemsetAsync(d_out, 0, (size_t)out_size * sizeof(float), stream);
  kW<<<4160, 256, 0, stream>>>(W1, W2, Wc, W1f, W2f, Wchf, Wclf);
  kLg<<<NGRP, 512, 0, stream>>>(x, Wchf, Wclf, bc, xb, sel, flags, cntr);
  kFix<<<1024, 64, 0, stream>>>(x, Wc, bc, sel, flags, cntr);
  kBm<<<NGRP, 256, 0, stream>>>(xb, W1f, b1, sel, innerb);
  for (int c = 0; c < NC; ++c) {
    kC1<<<Ec * 32, 256, 0, stream>>>(innerb, W2f, b2, Rb, c * Ec, Ec);
    kC2<<<NGRP * 4, 256, 0, stream>>>(Rb, sel, out, c * Ec, Ec, NC == 1);
  }
}